// Round 11
// baseline (635.185 us; speedup 1.0000x reference)
//
#include <hip/hip_runtime.h>
#include <hip/hip_bf16.h>

#define N_NODES   100000
#define N_EDGES   1600000
#define CH        128
#define N_GRAPHS  512
#define BN_EPS    1e-5f
#define N_PAD     100128   /* N_NODES rounded up past 128-row gemm tile */

typedef unsigned int uint;
typedef unsigned short ushort_t;

typedef short bf16x8 __attribute__((ext_vector_type(8)));
typedef float f32x4  __attribute__((ext_vector_type(4)));
typedef float f32x2  __attribute__((ext_vector_type(2)));

__device__ __forceinline__ ushort_t f2bf(float f) {
    uint u = __float_as_uint(f);
    uint r = (u + 0x7fffu + ((u >> 16) & 1u)) >> 16;   // round-to-nearest-even
    return (ushort_t)r;
}
__device__ __forceinline__ float bf2f(ushort_t u) {
    return __uint_as_float(((uint)u) << 16);
}
__device__ __forceinline__ float bf2f_lo(uint u) {      // low bf16 of a dword
    return __uint_as_float(u << 16);
}
__device__ __forceinline__ float bf2f_hi(uint u) {      // high bf16 of a dword
    return __uint_as_float(u & 0xffff0000u);
}

// ---------------- mega-fused prologue ----------------
// block ranges (LONGEST blocks FIRST so their latency hides under the 67us atomic
// stream; measured: deg-first = 90us, gemm-first = 81us):
//   [0, GEMM1_BLOCKS)               : layer-1 GEMM  H = x @ W1 (bf16, UNSCALED),
//                                     W1 staged to LDS in TWO 64-col halves (17 KB).
//   [GEMM1_BLOCKS, +PREP_W_BLOCKS)  : Wt[l][n*128+k] = bf16(W_{l+2}[k*128+n])  (layers 2,3)
//   rest                            : degree count + per-edge rank (atomic-bound ~67us)
// NOTE: no min-waves launch bound — round 7's (256,6) forced VGPR=40 and spilled.
#define GEMM1_BLOCKS  ((N_NODES + 127) / 128)   /* 782 */
#define PREP_W_BLOCKS 128
#define DEG_BLOCKS    ((N_EDGES + 255) / 256)   /* 6250 */
#define WLDS_PITCH 136   /* bf16 elems per LDS row */

__global__ __launch_bounds__(256) void k_prep(const int* __restrict__ dst,
                                              int* __restrict__ cnt,
                                              int* __restrict__ rank,
                                              const float* __restrict__ W1,
                                              const float* __restrict__ W2,
                                              const float* __restrict__ W3,
                                              ushort_t* __restrict__ Wt,
                                              const float* __restrict__ x,
                                              ushort_t* __restrict__ H) {
    __shared__ ushort_t lws[64 * WLDS_PITCH];     // 17408 B
    const int bid = blockIdx.x;

    if (bid < GEMM1_BLOCKS) {
        // ---- layer-1 GEMM, two 64-col halves ----
        const int blk = bid;
        const int t = threadIdx.x;
        const int wave = t >> 6;
        const int lane = t & 63;
        const int q = lane >> 4;
        const int r = lane & 15;
        const int row0 = blk * 128 + wave * 32;

        // build all A fragments once (f32 -> bf16 in-register)
        bf16x8 afrag[4][2];
#pragma unroll
        for (int i = 0; i < 2; ++i) {
            int rr = row0 + i * 16 + r;
            if (rr > N_NODES - 1) rr = N_NODES - 1;   // clamp: x is exactly N_NODES rows
            const float* rowp = x + (size_t)rr * 128;
#pragma unroll
            for (int ks = 0; ks < 4; ++ks) {
                const int k0 = ks * 32 + q * 8;
                float4 v0 = *(const float4*)(rowp + k0);
                float4 v1 = *(const float4*)(rowp + k0 + 4);
                bf16x8 av;
                av[0] = (short)f2bf(v0.x); av[1] = (short)f2bf(v0.y);
                av[2] = (short)f2bf(v0.z); av[3] = (short)f2bf(v0.w);
                av[4] = (short)f2bf(v1.x); av[5] = (short)f2bf(v1.y);
                av[6] = (short)f2bf(v1.z); av[7] = (short)f2bf(v1.w);
                afrag[ks][i] = av;
            }
        }

        for (int h = 0; h < 2; ++h) {
            if (h) __syncthreads();               // all reads of half 0 done
            // stage cols [h*64, h*64+64): lws[n_local][k] = bf16(W1[k][h*64+n_local])
            for (int it = 0; it < 32; ++it) {
                int e = it * 256 + t;             // < 8192
                int k = e >> 6;
                int n = e & 63;
                lws[n * WLDS_PITCH + k] = f2bf(W1[k * 128 + h * 64 + n]);
            }
            __syncthreads();

            f32x4 acc[2][4];
#pragma unroll
            for (int i = 0; i < 2; ++i)
#pragma unroll
                for (int j = 0; j < 4; ++j)
                    acc[i][j] = (f32x4){0.f, 0.f, 0.f, 0.f};

#pragma unroll
            for (int ks = 0; ks < 4; ++ks) {
                const int k0 = ks * 32 + q * 8;
                bf16x8 b[4];
#pragma unroll
                for (int jj = 0; jj < 4; ++jj)
                    b[jj] = *(const bf16x8*)&lws[(jj * 16 + r) * WLDS_PITCH + k0];
#pragma unroll
                for (int i = 0; i < 2; ++i)
#pragma unroll
                    for (int jj = 0; jj < 4; ++jj)
                        acc[i][jj] = __builtin_amdgcn_mfma_f32_16x16x32_bf16(afrag[ks][i], b[jj], acc[i][jj], 0, 0, 0);
            }

            // UNSCALED store of this half's 64 columns
#pragma unroll
            for (int i = 0; i < 2; ++i) {
#pragma unroll
                for (int rg = 0; rg < 4; ++rg) {
                    int rr = row0 + i * 16 + q * 4 + rg;
                    if (rr < N_NODES) {
#pragma unroll
                        for (int jj = 0; jj < 4; ++jj)
                            H[(size_t)rr * 128 + h * 64 + jj * 16 + r] = f2bf(acc[i][jj][rg]);
                    }
                }
            }
        }
        return;
    }

    if (bid < GEMM1_BLOCKS + PREP_W_BLOCKS) {
        int tid = (bid - GEMM1_BLOCKS) * 256 + threadIdx.x;   // < 2*16384
        int l = tid >> 14;                         // 0 -> W2, 1 -> W3
        int e = tid & 16383;
        int n = e >> 7;
        int k = e & 127;
        const float* W = l ? W3 : W2;
        Wt[l * 16384 + n * 128 + k] = f2bf(W[k * 128 + n]);
        return;
    }

    // ---- degree count + rank ----
    int e = (bid - GEMM1_BLOCKS - PREP_W_BLOCKS) * 256 + threadIdx.x;
    if (e < N_EDGES) rank[e] = atomicAdd(&cnt[dst[e]], 1);
}

// ---------------- scan step 1: per-512-block exclusive scan ----------------
__global__ __launch_bounds__(512) void k_scan1(const int* __restrict__ cnt,
                                               int* __restrict__ lofs,
                                               int* __restrict__ bsum) {
    __shared__ int sd[512];
    int t = threadIdx.x;
    int i = blockIdx.x * 512 + t;
    int v = (i < N_NODES) ? cnt[i] : 0;
    sd[t] = v;
    __syncthreads();
    for (int o = 1; o < 512; o <<= 1) {
        int x = (t >= o) ? sd[t - o] : 0;
        __syncthreads();
        sd[t] += x;
        __syncthreads();
    }
    if (i < N_NODES) lofs[i] = sd[t] - v;     // exclusive
    if (t == 511) bsum[blockIdx.x] = sd[511];
}

// ---------------- scan steps 2+3 fused: every block redundantly scans bsum (196 ints) ----------------
__global__ __launch_bounds__(256) void k_scan3(const int* __restrict__ lofs,
                                               const int* __restrict__ bsum,
                                               const int* __restrict__ cnt,
                                               int* __restrict__ offs,
                                               float* __restrict__ dinv,
                                               int nblocks) {
    __shared__ int sd[256];
    int t = threadIdx.x;
    int v = (t < nblocks) ? bsum[t] : 0;
    sd[t] = v;
    __syncthreads();
    for (int o = 1; o < 256; o <<= 1) {
        int x = (t >= o) ? sd[t - o] : 0;
        __syncthreads();
        sd[t] += x;
        __syncthreads();
    }
    int exc = sd[t] - v;               // exclusive
    __syncthreads();
    sd[t] = exc;
    __syncthreads();

    int i = blockIdx.x * 256 + t;
    if (i < N_NODES) {
        offs[i] = lofs[i] + sd[i >> 9];
        dinv[i] = rsqrtf((float)cnt[i] + 1.0f);
    }
    if (i == 0) offs[N_NODES] = N_EDGES;
}

// ---------------- CSR fill (no atomics: rank precomputed) ----------------
__global__ __launch_bounds__(256) void k_fill(const int* __restrict__ src,
                                              const int* __restrict__ dst,
                                              const int* __restrict__ offs,
                                              const int* __restrict__ rank,
                                              int* __restrict__ csr_src) {
    int e = blockIdx.x * 256 + threadIdx.x;
    if (e >= N_EDGES) return;
    int pos = offs[dst[e]] + rank[e];
    csr_src[pos] = src[e];
}

// ---------------- MFMA GEMM (layers 2,3): Hs(bf16) = dinv * (A @ W) ----------------
// Two-phase: phase 1 builds all A-fragments with fused bn_apply (+residual for MODE 3)
// and writes the activation XOUT; phase 2 is a clean B-load + MFMA loop.
template<int MODE>   // 2: relu(bn(AGG)); 3: relu(bn(AGG)+RES)
__global__ __launch_bounds__(256) void k_gemm(const ushort_t* __restrict__ Ain,
                                              const ushort_t* __restrict__ Wt,
                                              const float* __restrict__ dinv,
                                              ushort_t* __restrict__ H,
                                              const float* __restrict__ stats,
                                              const float* __restrict__ gamma,
                                              const float* __restrict__ beta,
                                              const ushort_t* __restrict__ RES,
                                              ushort_t* __restrict__ XOUT) {
    const int t = threadIdx.x;
    const int wave = t >> 6;
    const int lane = t & 63;
    const int q = lane >> 4;
    const int r = lane & 15;
    const int row0 = blockIdx.x * 128 + wave * 32;

    bf16x8 afrag[4][2];
    const float invN = 1.0f / (float)N_NODES;

#pragma unroll
    for (int ks = 0; ks < 4; ++ks) {
        const int k0 = ks * 32 + q * 8;
        float sc[8], sh[8];
        {
            float4 sm0 = *(const float4*)&stats[k0];
            float4 sm1 = *(const float4*)&stats[k0 + 4];
            float4 sq0 = *(const float4*)&stats[128 + k0];
            float4 sq1 = *(const float4*)&stats[128 + k0 + 4];
            float4 gm0 = *(const float4*)&gamma[k0];
            float4 gm1 = *(const float4*)&gamma[k0 + 4];
            float4 bt0 = *(const float4*)&beta[k0];
            float4 bt1 = *(const float4*)&beta[k0 + 4];
            float sm[8] = {sm0.x, sm0.y, sm0.z, sm0.w, sm1.x, sm1.y, sm1.z, sm1.w};
            float sq[8] = {sq0.x, sq0.y, sq0.z, sq0.w, sq1.x, sq1.y, sq1.z, sq1.w};
            float gm[8] = {gm0.x, gm0.y, gm0.z, gm0.w, gm1.x, gm1.y, gm1.z, gm1.w};
            float bt[8] = {bt0.x, bt0.y, bt0.z, bt0.w, bt1.x, bt1.y, bt1.z, bt1.w};
#pragma unroll
            for (int u = 0; u < 8; ++u) {
                float mu = sm[u] * invN;
                float s  = gm[u] * rsqrtf(sq[u] * invN - mu * mu + BN_EPS);
                sc[u] = s;
                sh[u] = bt[u] - mu * s;
            }
        }
#pragma unroll
        for (int i = 0; i < 2; ++i) {
            int row = row0 + i * 16 + r;
            int rrc = (row < N_NODES) ? row : (N_NODES - 1);
            uint4 av = *(const uint4*)(Ain + (size_t)rrc * 128 + k0);
            float y[8];
            y[0] = bf2f_lo(av.x); y[1] = bf2f_hi(av.x);
            y[2] = bf2f_lo(av.y); y[3] = bf2f_hi(av.y);
            y[4] = bf2f_lo(av.z); y[5] = bf2f_hi(av.z);
            y[6] = bf2f_lo(av.w); y[7] = bf2f_hi(av.w);
#pragma unroll
            for (int u = 0; u < 8; ++u) y[u] = y[u] * sc[u] + sh[u];
            if constexpr (MODE == 3) {
                uint4 rv = *(const uint4*)(RES + (size_t)rrc * 128 + k0);
                y[0] += bf2f_lo(rv.x); y[1] += bf2f_hi(rv.x);
                y[2] += bf2f_lo(rv.y); y[3] += bf2f_hi(rv.y);
                y[4] += bf2f_lo(rv.z); y[5] += bf2f_hi(rv.z);
                y[6] += bf2f_lo(rv.w); y[7] += bf2f_hi(rv.w);
            }
            uint4 o;
            o.x = (uint)f2bf(fmaxf(y[0], 0.f)) | ((uint)f2bf(fmaxf(y[1], 0.f)) << 16);
            o.y = (uint)f2bf(fmaxf(y[2], 0.f)) | ((uint)f2bf(fmaxf(y[3], 0.f)) << 16);
            o.z = (uint)f2bf(fmaxf(y[4], 0.f)) | ((uint)f2bf(fmaxf(y[5], 0.f)) << 16);
            o.w = (uint)f2bf(fmaxf(y[6], 0.f)) | ((uint)f2bf(fmaxf(y[7], 0.f)) << 16);
            afrag[ks][i] = __builtin_bit_cast(bf16x8, o);
            if (row < N_NODES)
                *(uint4*)(XOUT + (size_t)row * 128 + k0) = o;
        }
    }

    f32x4 acc[2][8];
#pragma unroll
    for (int i = 0; i < 2; ++i)
#pragma unroll
        for (int j = 0; j < 8; ++j)
            acc[i][j] = (f32x4){0.f, 0.f, 0.f, 0.f};

#pragma unroll
    for (int ks = 0; ks < 4; ++ks) {
        const int k0 = ks * 32 + q * 8;
        bf16x8 b[8];
#pragma unroll
        for (int j = 0; j < 8; ++j)
            b[j] = *(const bf16x8*)(Wt + (size_t)(j * 16 + r) * 128 + k0);
#pragma unroll
        for (int i = 0; i < 2; ++i)
#pragma unroll
            for (int j = 0; j < 8; ++j)
                acc[i][j] = __builtin_amdgcn_mfma_f32_16x16x32_bf16(afrag[ks][i], b[j], acc[i][j], 0, 0, 0);
    }

#pragma unroll
    for (int i = 0; i < 2; ++i) {
#pragma unroll
        for (int rg = 0; rg < 4; ++rg) {
            int rr = row0 + i * 16 + q * 4 + rg;
            if (rr < N_NODES) {
                float dv = dinv[rr];
#pragma unroll
                for (int j = 0; j < 8; ++j)
                    H[(size_t)rr * 128 + j * 16 + r] = f2bf(acc[i][j][rg] * dv);
            }
        }
    }
}

// ---------------- gather-aggregate v4: one wave per dst node, 4 edges per pass ----------------
// 16 lanes per edge, uint4 (16B) loads; 32-edge unrolled main loop (8 loads in
// flight) + packed f32x2 accumulation (v_pk_add_f32 / v_pk_fma_f32).
// PRESCALED (layers 2,3): H rows already carry dinv_src ->
//     AGG = dinv_i*(sum H[s] + H[i]) + b
// !PRESCALED (layer 1): H unscaled ->
//     AGG = dinv_i*(sum dinv_s*H[s] + dinv_i*H[i]) + b
template<bool PRESCALED>
__global__ __launch_bounds__(256) void k_gather(const int* __restrict__ csr_src,
                                                const int* __restrict__ offs,
                                                const float* __restrict__ dinv,
                                                const ushort_t* __restrict__ H,
                                                const float* __restrict__ b,
                                                ushort_t* __restrict__ AGG) {
    int node = blockIdx.x * 4 + (threadIdx.x >> 6);
    if (node >= N_NODES) return;
    int lane = threadIdx.x & 63;
    int g = lane >> 4;             // edge slot within the quad (0..3)
    int cl = lane & 15;
    int c = cl * 8;                // 8 channels per lane

    f32x2 A01 = (f32x2){0.f, 0.f}, A23 = (f32x2){0.f, 0.f};
    f32x2 A45 = (f32x2){0.f, 0.f}, A67 = (f32x2){0.f, 0.f};
    float dvn = dinv[node];

#define ACC8(hv)  do { \
        A01 += (f32x2){bf2f_lo((hv).x), bf2f_hi((hv).x)}; \
        A23 += (f32x2){bf2f_lo((hv).y), bf2f_hi((hv).y)}; \
        A45 += (f32x2){bf2f_lo((hv).z), bf2f_hi((hv).z)}; \
        A67 += (f32x2){bf2f_lo((hv).w), bf2f_hi((hv).w)}; } while (0)
#define ACC8F(hv, dv)  do { \
        f32x2 dv2 = (f32x2){(dv), (dv)}; \
        A01 += (f32x2){bf2f_lo((hv).x), bf2f_hi((hv).x)} * dv2; \
        A23 += (f32x2){bf2f_lo((hv).y), bf2f_hi((hv).y)} * dv2; \
        A45 += (f32x2){bf2f_lo((hv).z), bf2f_hi((hv).z)} * dv2; \
        A67 += (f32x2){bf2f_lo((hv).w), bf2f_hi((hv).w)} * dv2; } while (0)

    if (g == 0) {                  // self term
        uint4 hv = *(const uint4*)(H + (size_t)node * 128 + c);
        if constexpr (PRESCALED) { ACC8(hv); } else { ACC8F(hv, dvn); }
    }

    int p = offs[node];
    int end = offs[node + 1];

    for (; p + 32 <= end; p += 32) {          // 32 edges: 8 quad-loads in flight
        int s[8];
#pragma unroll
        for (int k = 0; k < 8; ++k) s[k] = csr_src[p + 4 * k + g];
        uint4 h[8];
#pragma unroll
        for (int k = 0; k < 8; ++k) h[k] = *(const uint4*)(H + (size_t)s[k] * 128 + c);
        if constexpr (PRESCALED) {
#pragma unroll
            for (int k = 0; k < 8; ++k) ACC8(h[k]);
        } else {
            float d[8];
#pragma unroll
            for (int k = 0; k < 8; ++k) d[k] = dinv[s[k]];
#pragma unroll
            for (int k = 0; k < 8; ++k) ACC8F(h[k], d[k]);
        }
    }
    for (; p + 16 <= end; p += 16) {          // 16 edges: 4 quad-loads in flight
        int s0 = csr_src[p      + g], s1 = csr_src[p +  4 + g];
        int s2 = csr_src[p +  8 + g], s3 = csr_src[p + 12 + g];
        uint4 h0 = *(const uint4*)(H + (size_t)s0 * 128 + c);
        uint4 h1 = *(const uint4*)(H + (size_t)s1 * 128 + c);
        uint4 h2 = *(const uint4*)(H + (size_t)s2 * 128 + c);
        uint4 h3 = *(const uint4*)(H + (size_t)s3 * 128 + c);
        if constexpr (PRESCALED) {
            ACC8(h0); ACC8(h1); ACC8(h2); ACC8(h3);
        } else {
            float d0 = dinv[s0], d1 = dinv[s1], d2 = dinv[s2], d3 = dinv[s3];
            ACC8F(h0, d0); ACC8F(h1, d1); ACC8F(h2, d2); ACC8F(h3, d3);
        }
    }
    for (; p + 4 <= end; p += 4) {            // 4 edges: 1 quad-load
        int s0 = csr_src[p + g];
        uint4 h0 = *(const uint4*)(H + (size_t)s0 * 128 + c);
        if constexpr (PRESCALED) { ACC8(h0); }
        else { float d0 = dinv[s0]; ACC8F(h0, d0); }
    }
    if (p < end) {                            // tail: 1-3 edges, predicated
        int idx = p + g;
        bool ok = idx < end;
        int s0 = csr_src[ok ? idx : p];
        uint4 h0 = *(const uint4*)(H + (size_t)s0 * 128 + c);
        if (ok) {
            if constexpr (PRESCALED) { ACC8(h0); }
            else { float d0 = dinv[s0]; ACC8F(h0, d0); }
        }
    }
#undef ACC8
#undef ACC8F

    float a0 = A01[0], a1 = A01[1], a2 = A23[0], a3 = A23[1];
    float a4 = A45[0], a5 = A45[1], a6 = A67[0], a7 = A67[1];

    // combine the 4 edge groups: xor 16 then xor 32
    a0 += __shfl_xor(a0, 16); a1 += __shfl_xor(a1, 16);
    a2 += __shfl_xor(a2, 16); a3 += __shfl_xor(a3, 16);
    a4 += __shfl_xor(a4, 16); a5 += __shfl_xor(a5, 16);
    a6 += __shfl_xor(a6, 16); a7 += __shfl_xor(a7, 16);
    a0 += __shfl_xor(a0, 32); a1 += __shfl_xor(a1, 32);
    a2 += __shfl_xor(a2, 32); a3 += __shfl_xor(a3, 32);
    a4 += __shfl_xor(a4, 32); a5 += __shfl_xor(a5, 32);
    a6 += __shfl_xor(a6, 32); a7 += __shfl_xor(a7, 32);

    if (g == 0) {
        float4 bv0 = *(const float4*)&b[c];
        float4 bv1 = *(const float4*)&b[c + 4];
        a0 = a0 * dvn + bv0.x; a1 = a1 * dvn + bv0.y;
        a2 = a2 * dvn + bv0.z; a3 = a3 * dvn + bv0.w;
        a4 = a4 * dvn + bv1.x; a5 = a5 * dvn + bv1.y;
        a6 = a6 * dvn + bv1.z; a7 = a7 * dvn + bv1.w;
        uint4 o;
        o.x = (uint)f2bf(a0) | ((uint)f2bf(a1) << 16);
        o.y = (uint)f2bf(a2) | ((uint)f2bf(a3) << 16);
        o.z = (uint)f2bf(a4) | ((uint)f2bf(a5) << 16);
        o.w = (uint)f2bf(a6) | ((uint)f2bf(a7) << 16);
        *(uint4*)(AGG + (size_t)node * 128 + c) = o;
    }
}

// ---------------- BN stats v2: uint2 loads, 16-way LDS reduce, 1 atomic/ch/block ----------------
// grid 256 (was 512): halves the device-scope atomic stream (131K->65K);
// 256 blocks x 8 waves still saturate the 25.6MB read.
__global__ __launch_bounds__(512) void k_bn_stats(const ushort_t* __restrict__ AGG,
                                                  float* __restrict__ stats) {
    __shared__ float red[2][16][128];
    int c4 = (threadIdx.x & 31) * 4;
    int rl = threadIdx.x >> 5;          // 0..15 row-lanes
    float s0 = 0.f, s1 = 0.f, s2 = 0.f, s3 = 0.f;
    float q0 = 0.f, q1 = 0.f, q2 = 0.f, q3 = 0.f;
    for (int i = blockIdx.x * 16 + rl; i < N_NODES; i += gridDim.x * 16) {
        uint2 av = *(const uint2*)&AGG[(size_t)i * 128 + c4];
        float v0 = bf2f_lo(av.x), v1 = bf2f_hi(av.x);
        float v2 = bf2f_lo(av.y), v3 = bf2f_hi(av.y);
        s0 += v0; q0 += v0 * v0;
        s1 += v1; q1 += v1 * v1;
        s2 += v2; q2 += v2 * v2;
        s3 += v3; q3 += v3 * v3;
    }
    red[0][rl][c4 + 0] = s0; red[0][rl][c4 + 1] = s1;
    red[0][rl][c4 + 2] = s2; red[0][rl][c4 + 3] = s3;
    red[1][rl][c4 + 0] = q0; red[1][rl][c4 + 1] = q1;
    red[1][rl][c4 + 2] = q2; red[1][rl][c4 + 3] = q3;
    __syncthreads();
    int t = threadIdx.x;
    if (t < 128) {
        float S = 0.f;
#pragma unroll
        for (int k = 0; k < 16; ++k) S += red[0][k][t];
        atomicAdd(&stats[t], S);
    } else if (t < 256) {
        int c = t - 128;
        float Q = 0.f;
#pragma unroll
        for (int k = 0; k < 16; ++k) Q += red[1][k][c];
        atomicAdd(&stats[128 + c], Q);
    }
}

// ---------------- pooling v3: one block per graph, no atomics, head FUSED ----------------
// fused layer-3 bn_apply + relu + residual; per-graph range via binary search;
// head GEMV computed from LDS (psum/pmax never hit global).
__global__ __launch_bounds__(512) void k_pool(const ushort_t* __restrict__ AGG,
                                              const ushort_t* __restrict__ RES,
                                              const float* __restrict__ stats,
                                              const float* __restrict__ gamma,
                                              const float* __restrict__ beta,
                                              const int* __restrict__ batch,
                                              const float* __restrict__ Wh,
                                              const float* __restrict__ bh,
                                              float* __restrict__ out) {
    __shared__ int se[2];
    __shared__ float rs[16][128];
    __shared__ float rm[16][128];
    __shared__ float hp[8][64];
    int g = blockIdx.x;
    if (threadIdx.x < 2) {
        int target = g + (int)threadIdx.x;      // lower_bound(batch, target)
        int lo = 0, hi = N_NODES;
        while (lo < hi) {
            int mid = (lo + hi) >> 1;
            if (batch[mid] < target) lo = mid + 1; else hi = mid;
        }
        se[threadIdx.x] = lo;
    }
    __syncthreads();
    int i0 = se[0], i1 = se[1];

    int c4 = (threadIdx.x & 31) * 4;
    int rl = threadIdx.x >> 5;                  // 0..15

    const float invN = 1.0f / (float)N_NODES;
    float sc[4], sh[4];
#pragma unroll
    for (int u = 0; u < 4; ++u) {
        float mu = stats[c4 + u] * invN;
        float s = gamma[c4 + u] * rsqrtf(stats[128 + c4 + u] * invN - mu * mu + BN_EPS);
        sc[u] = s;
        sh[u] = beta[c4 + u] - mu * s;
    }

    float s0 = 0.f, s1 = 0.f, s2 = 0.f, s3 = 0.f;
    float m0 = 0.f, m1 = 0.f, m2 = 0.f, m3 = 0.f;
    for (int i = i0 + rl; i < i1; i += 16) {
        uint2 av = *(const uint2*)&AGG[(size_t)i * 128 + c4];
        uint2 rv = *(const uint2*)&RES[(size_t)i * 128 + c4];
        float v0 = fmaxf(bf2f_lo(av.x) * sc[0] + sh[0] + bf2f_lo(rv.x), 0.f);
        float v1 = fmaxf(bf2f_hi(av.x) * sc[1] + sh[1] + bf2f_hi(rv.x), 0.f);
        float v2 = fmaxf(bf2f_lo(av.y) * sc[2] + sh[2] + bf2f_lo(rv.y), 0.f);
        float v3 = fmaxf(bf2f_hi(av.y) * sc[3] + sh[3] + bf2f_hi(rv.y), 0.f);
        s0 += v0; m0 = fmaxf(m0, v0);
        s1 += v1; m1 = fmaxf(m1, v1);
        s2 += v2; m2 = fmaxf(m2, v2);
        s3 += v3; m3 = fmaxf(m3, v3);
    }
    rs[rl][c4 + 0] = s0; rs[rl][c4 + 1] = s1; rs[rl][c4 + 2] = s2; rs[rl][c4 + 3] = s3;
    rm[rl][c4 + 0] = m0; rm[rl][c4 + 1] = m1; rm[rl][c4 + 2] = m2; rm[rl][c4 + 3] = m3;
    __syncthreads();
    int t = threadIdx.x;
    if (t < 128) {
        float S = 0.f, M = 0.f;
#pragma unroll
        for (int k = 0; k < 16; ++k) {
            S += rs[k][t];
            M = fmaxf(M, rm[k][t]);
        }
        rs[0][t] = S;        // final per-channel sum
        rm[0][t] = M;        // final per-channel max
    }
    __syncthreads();

    // ---- fused head: out[g][o] = bh[o] + sum_c mean*Wh[c][o] + S*Wh[128+c][o] + M*Wh[256+c][o]
    float inv = 1.0f / fmaxf((float)(i1 - i0), 1.0f);
    int o = t & 63;
    int kc = t >> 6;                            // 0..7, 16 channels each
    float acc = 0.f;
#pragma unroll
    for (int u = 0; u < 16; ++u) {
        int c = kc * 16 + u;
        float S = rs[0][c];
        float M = rm[0][c];
        acc += (S * inv) * Wh[c * 64 + o];
        acc += S * Wh[(128 + c) * 64 + o];
        acc += M * Wh[(256 + c) * 64 + o];
    }
    hp[kc][o] = acc;
    __syncthreads();
    if (t < 64) {
        float r = bh[t];
#pragma unroll
        for (int k = 0; k < 8; ++k) r += hp[k][t];
        out[g * 64 + t] = r;
    }
}

// ---------------- host orchestration ----------------
extern "C" void kernel_launch(void* const* d_in, const int* in_sizes, int n_in,
                              void* d_out, int out_size, void* d_ws, size_t ws_size,
                              hipStream_t stream) {
    const float* x     = (const float*)d_in[0];
    const int*   ei    = (const int*)d_in[1];
    const int*   batch = (const int*)d_in[2];
    const float* W1 = (const float*)d_in[3];
    const float* b1 = (const float*)d_in[4];
    const float* g1 = (const float*)d_in[5];
    const float* be1= (const float*)d_in[6];
    const float* W2 = (const float*)d_in[7];
    const float* b2 = (const float*)d_in[8];
    const float* g2 = (const float*)d_in[9];
    const float* be2= (const float*)d_in[10];
    const float* W3 = (const float*)d_in[11];
    const float* b3 = (const float*)d_in[12];
    const float* g3 = (const float*)d_in[13];
    const float* be3= (const float*)d_in[14];
    const float* Wh = (const float*)d_in[15];
    const float* bh = (const float*)d_in[16];

    const int* src = ei;
    const int* dst = ei + N_EDGES;

    char* ws = (char*)d_ws;
    size_t off = 0;

    // ---- zero-initialized contiguous region (single memset) ----
    char* zero_base = ws;
    int*   cnt     = (int*)(ws + off);      off += 400384;                       // N_NODES*4 padded
    float* stats   = (float*)(ws + off);    off += 3 * 512 * 4;                  // 3 layers x 512 floats
    size_t zero_bytes = off;

    // ---- uninitialized scratch ----
    float* dinv    = (float*)(ws + off);    off += 512 * 1024;
    ushort_t* XBA  = (ushort_t*)(ws + off); off += (size_t)N_PAD * CH * 2;
    ushort_t* XBB  = (ushort_t*)(ws + off); off += (size_t)N_PAD * CH * 2;
    ushort_t* H    = (ushort_t*)(ws + off); off += (size_t)N_PAD * CH * 2;
    ushort_t* AGG  = (ushort_t*)(ws + off); off += (size_t)N_NODES * CH * 2;
    ushort_t* Wt   = (ushort_t*)(ws + off); off += 2 * 16384 * 2;               // layers 2,3 only
    int*   lofs    = (int*)(ws + off);      off += 512 * 1024;
    int*   offs    = (int*)(ws + off);      off += 512 * 1024;      // N+1 ints
    int*   bsum    = (int*)(ws + off);      off += 4096;
    int*   rank    = (int*)(ws + off);      off += (size_t)N_EDGES * 4;
    int*   csr_src = (int*)(ws + off);      off += (size_t)N_EDGES * 4;

    const int SCAN_BLOCKS = (N_NODES + 511) / 512;   // 196

    hipMemsetAsync(zero_base, 0, zero_bytes, stream);

    // mega-fused: layer-1 GEMM (FIRST: longest blocks) + W2/W3 transpose + degree count
    k_prep<<<GEMM1_BLOCKS + PREP_W_BLOCKS + DEG_BLOCKS, 256, 0, stream>>>(
        dst, cnt, rank, W1, W2, W3, Wt, x, H);

    k_scan1<<<SCAN_BLOCKS, 512, 0, stream>>>(cnt, lofs, bsum);
    k_scan3<<<(N_NODES + 255) / 256, 256, 0, stream>>>(lofs, bsum, cnt, offs, dinv, SCAN_BLOCKS);
    k_fill<<<(N_EDGES + 255) / 256, 256, 0, stream>>>(src, dst, offs, rank, csr_src);

    const int gemm_grid   = (N_NODES + 127) / 128;   // 782
    const int gather_grid = (N_NODES + 3) / 4;

    float* st1 = stats;
    float* st2 = stats + 512;
    float* st3 = stats + 1024;

    // layer 1 aggregation (H unscaled -> per-edge dinv fma)
    k_gather<false><<<gather_grid, 256, 0, stream>>>(csr_src, offs, dinv, H, b1, AGG);
    k_bn_stats<<<256, 512, 0, stream>>>(AGG, st1);

    // layer 2: A = relu(bn1(AGG)) in-register; writes h1 -> XBB
    k_gemm<2><<<gemm_grid, 256, 0, stream>>>(AGG, Wt, dinv, H,
                                             st1, g1, be1, nullptr, XBB);
    k_gather<true><<<gather_grid, 256, 0, stream>>>(csr_src, offs, dinv, H, b2, AGG);
    k_bn_stats<<<256, 512, 0, stream>>>(AGG, st2);

    // layer 3: A = relu(bn2(AGG) + h1) in-register; writes h2 -> XBA
    k_gemm<3><<<gemm_grid, 256, 0, stream>>>(AGG, Wt + 16384, dinv, H,
                                             st2, g2, be2, XBB, XBA);
    k_gather<true><<<gather_grid, 256, 0, stream>>>(csr_src, offs, dinv, H, b3, AGG);
    k_bn_stats<<<256, 512, 0, stream>>>(AGG, st3);

    // pooling (fused layer-3 bn_apply + relu + residual(h2) + HEAD), no atomics
    k_pool<<<N_GRAPHS, 512, 0, stream>>>(AGG, XBA, st3, g3, be3, batch, Wh, bh, (float*)d_out);
}

// Round 12
// 556.874 us; speedup vs baseline: 1.1406x; 1.1406x over previous
//
#include <hip/hip_runtime.h>
#include <hip/hip_bf16.h>

#define N_NODES   100000
#define N_EDGES   1600000
#define CH        128
#define N_GRAPHS  512
#define BN_EPS    1e-5f
#define N_PAD     100128   /* N_NODES rounded up past 128-row gemm tile */

typedef unsigned int uint;
typedef unsigned short ushort_t;

typedef short bf16x8 __attribute__((ext_vector_type(8)));
typedef float f32x4  __attribute__((ext_vector_type(4)));

__device__ __forceinline__ ushort_t f2bf(float f) {
    uint u = __float_as_uint(f);
    uint r = (u + 0x7fffu + ((u >> 16) & 1u)) >> 16;   // round-to-nearest-even
    return (ushort_t)r;
}
__device__ __forceinline__ float bf2f(ushort_t u) {
    return __uint_as_float(((uint)u) << 16);
}
__device__ __forceinline__ float bf2f_lo(uint u) {      // low bf16 of a dword
    return __uint_as_float(u << 16);
}
__device__ __forceinline__ float bf2f_hi(uint u) {      // high bf16 of a dword
    return __uint_as_float(u & 0xffff0000u);
}

// ---------------- mega-fused prologue ----------------
// block ranges (LONGEST blocks FIRST so their latency hides under the 67us atomic
// stream; measured: deg-first = 90us, gemm-first = 81us):
//   [0, GEMM1_BLOCKS)               : layer-1 GEMM  H = x @ W1 (bf16, UNSCALED),
//                                     W1 staged to LDS in TWO 64-col halves (17 KB).
//   [GEMM1_BLOCKS, +PREP_W_BLOCKS)  : Wt[l][n*128+k] = bf16(W_{l+2}[k*128+n])  (layers 2,3)
//   rest                            : degree count + per-edge rank (atomic-bound ~67us)
// NOTE: no min-waves launch bound — round 7's (256,6) forced VGPR=40 and spilled.
// NOTE: k_gather is the round-10 form (VGPR 24, occ ~70%) — round 11's 32-edge
// unroll raised VGPR to 52, occupancy 70->37.5%, dur 65.6->106us. The gather is
// latency-bound: TLP >> per-wave ILP. Do not deepen its unroll.
#define GEMM1_BLOCKS  ((N_NODES + 127) / 128)   /* 782 */
#define PREP_W_BLOCKS 128
#define DEG_BLOCKS    ((N_EDGES + 255) / 256)   /* 6250 */
#define WLDS_PITCH 136   /* bf16 elems per LDS row */

__global__ __launch_bounds__(256) void k_prep(const int* __restrict__ dst,
                                              int* __restrict__ cnt,
                                              int* __restrict__ rank,
                                              const float* __restrict__ W1,
                                              const float* __restrict__ W2,
                                              const float* __restrict__ W3,
                                              ushort_t* __restrict__ Wt,
                                              const float* __restrict__ x,
                                              ushort_t* __restrict__ H) {
    __shared__ ushort_t lws[64 * WLDS_PITCH];     // 17408 B
    const int bid = blockIdx.x;

    if (bid < GEMM1_BLOCKS) {
        // ---- layer-1 GEMM, two 64-col halves ----
        const int blk = bid;
        const int t = threadIdx.x;
        const int wave = t >> 6;
        const int lane = t & 63;
        const int q = lane >> 4;
        const int r = lane & 15;
        const int row0 = blk * 128 + wave * 32;

        // build all A fragments once (f32 -> bf16 in-register)
        bf16x8 afrag[4][2];
#pragma unroll
        for (int i = 0; i < 2; ++i) {
            int rr = row0 + i * 16 + r;
            if (rr > N_NODES - 1) rr = N_NODES - 1;   // clamp: x is exactly N_NODES rows
            const float* rowp = x + (size_t)rr * 128;
#pragma unroll
            for (int ks = 0; ks < 4; ++ks) {
                const int k0 = ks * 32 + q * 8;
                float4 v0 = *(const float4*)(rowp + k0);
                float4 v1 = *(const float4*)(rowp + k0 + 4);
                bf16x8 av;
                av[0] = (short)f2bf(v0.x); av[1] = (short)f2bf(v0.y);
                av[2] = (short)f2bf(v0.z); av[3] = (short)f2bf(v0.w);
                av[4] = (short)f2bf(v1.x); av[5] = (short)f2bf(v1.y);
                av[6] = (short)f2bf(v1.z); av[7] = (short)f2bf(v1.w);
                afrag[ks][i] = av;
            }
        }

        for (int h = 0; h < 2; ++h) {
            if (h) __syncthreads();               // all reads of half 0 done
            // stage cols [h*64, h*64+64): lws[n_local][k] = bf16(W1[k][h*64+n_local])
            for (int it = 0; it < 32; ++it) {
                int e = it * 256 + t;             // < 8192
                int k = e >> 6;
                int n = e & 63;
                lws[n * WLDS_PITCH + k] = f2bf(W1[k * 128 + h * 64 + n]);
            }
            __syncthreads();

            f32x4 acc[2][4];
#pragma unroll
            for (int i = 0; i < 2; ++i)
#pragma unroll
                for (int j = 0; j < 4; ++j)
                    acc[i][j] = (f32x4){0.f, 0.f, 0.f, 0.f};

#pragma unroll
            for (int ks = 0; ks < 4; ++ks) {
                const int k0 = ks * 32 + q * 8;
                bf16x8 b[4];
#pragma unroll
                for (int jj = 0; jj < 4; ++jj)
                    b[jj] = *(const bf16x8*)&lws[(jj * 16 + r) * WLDS_PITCH + k0];
#pragma unroll
                for (int i = 0; i < 2; ++i)
#pragma unroll
                    for (int jj = 0; jj < 4; ++jj)
                        acc[i][jj] = __builtin_amdgcn_mfma_f32_16x16x32_bf16(afrag[ks][i], b[jj], acc[i][jj], 0, 0, 0);
            }

            // UNSCALED store of this half's 64 columns
#pragma unroll
            for (int i = 0; i < 2; ++i) {
#pragma unroll
                for (int rg = 0; rg < 4; ++rg) {
                    int rr = row0 + i * 16 + q * 4 + rg;
                    if (rr < N_NODES) {
#pragma unroll
                        for (int jj = 0; jj < 4; ++jj)
                            H[(size_t)rr * 128 + h * 64 + jj * 16 + r] = f2bf(acc[i][jj][rg]);
                    }
                }
            }
        }
        return;
    }

    if (bid < GEMM1_BLOCKS + PREP_W_BLOCKS) {
        int tid = (bid - GEMM1_BLOCKS) * 256 + threadIdx.x;   // < 2*16384
        int l = tid >> 14;                         // 0 -> W2, 1 -> W3
        int e = tid & 16383;
        int n = e >> 7;
        int k = e & 127;
        const float* W = l ? W3 : W2;
        Wt[l * 16384 + n * 128 + k] = f2bf(W[k * 128 + n]);
        return;
    }

    // ---- degree count + rank ----
    int e = (bid - GEMM1_BLOCKS - PREP_W_BLOCKS) * 256 + threadIdx.x;
    if (e < N_EDGES) rank[e] = atomicAdd(&cnt[dst[e]], 1);
}

// ---------------- scan step 1: per-512-block exclusive scan ----------------
__global__ __launch_bounds__(512) void k_scan1(const int* __restrict__ cnt,
                                               int* __restrict__ lofs,
                                               int* __restrict__ bsum) {
    __shared__ int sd[512];
    int t = threadIdx.x;
    int i = blockIdx.x * 512 + t;
    int v = (i < N_NODES) ? cnt[i] : 0;
    sd[t] = v;
    __syncthreads();
    for (int o = 1; o < 512; o <<= 1) {
        int x = (t >= o) ? sd[t - o] : 0;
        __syncthreads();
        sd[t] += x;
        __syncthreads();
    }
    if (i < N_NODES) lofs[i] = sd[t] - v;     // exclusive
    if (t == 511) bsum[blockIdx.x] = sd[511];
}

// ---------------- scan steps 2+3 fused: every block redundantly scans bsum (196 ints) ----------------
__global__ __launch_bounds__(256) void k_scan3(const int* __restrict__ lofs,
                                               const int* __restrict__ bsum,
                                               const int* __restrict__ cnt,
                                               int* __restrict__ offs,
                                               float* __restrict__ dinv,
                                               int nblocks) {
    __shared__ int sd[256];
    int t = threadIdx.x;
    int v = (t < nblocks) ? bsum[t] : 0;
    sd[t] = v;
    __syncthreads();
    for (int o = 1; o < 256; o <<= 1) {
        int x = (t >= o) ? sd[t - o] : 0;
        __syncthreads();
        sd[t] += x;
        __syncthreads();
    }
    int exc = sd[t] - v;               // exclusive
    __syncthreads();
    sd[t] = exc;
    __syncthreads();

    int i = blockIdx.x * 256 + t;
    if (i < N_NODES) {
        offs[i] = lofs[i] + sd[i >> 9];
        dinv[i] = rsqrtf((float)cnt[i] + 1.0f);
    }
    if (i == 0) offs[N_NODES] = N_EDGES;
}

// ---------------- CSR fill (no atomics: rank precomputed) ----------------
__global__ __launch_bounds__(256) void k_fill(const int* __restrict__ src,
                                              const int* __restrict__ dst,
                                              const int* __restrict__ offs,
                                              const int* __restrict__ rank,
                                              int* __restrict__ csr_src) {
    int e = blockIdx.x * 256 + threadIdx.x;
    if (e >= N_EDGES) return;
    int pos = offs[dst[e]] + rank[e];
    csr_src[pos] = src[e];
}

// ---------------- MFMA GEMM (layers 2,3): Hs(bf16) = dinv * (A @ W) ----------------
// Two-phase: phase 1 builds all A-fragments with fused bn_apply (+residual for MODE 3)
// and writes the activation XOUT; phase 2 is a clean B-load + MFMA loop.
template<int MODE>   // 2: relu(bn(AGG)); 3: relu(bn(AGG)+RES)
__global__ __launch_bounds__(256) void k_gemm(const ushort_t* __restrict__ Ain,
                                              const ushort_t* __restrict__ Wt,
                                              const float* __restrict__ dinv,
                                              ushort_t* __restrict__ H,
                                              const float* __restrict__ stats,
                                              const float* __restrict__ gamma,
                                              const float* __restrict__ beta,
                                              const ushort_t* __restrict__ RES,
                                              ushort_t* __restrict__ XOUT) {
    const int t = threadIdx.x;
    const int wave = t >> 6;
    const int lane = t & 63;
    const int q = lane >> 4;
    const int r = lane & 15;
    const int row0 = blockIdx.x * 128 + wave * 32;

    bf16x8 afrag[4][2];
    const float invN = 1.0f / (float)N_NODES;

#pragma unroll
    for (int ks = 0; ks < 4; ++ks) {
        const int k0 = ks * 32 + q * 8;
        float sc[8], sh[8];
        {
            float4 sm0 = *(const float4*)&stats[k0];
            float4 sm1 = *(const float4*)&stats[k0 + 4];
            float4 sq0 = *(const float4*)&stats[128 + k0];
            float4 sq1 = *(const float4*)&stats[128 + k0 + 4];
            float4 gm0 = *(const float4*)&gamma[k0];
            float4 gm1 = *(const float4*)&gamma[k0 + 4];
            float4 bt0 = *(const float4*)&beta[k0];
            float4 bt1 = *(const float4*)&beta[k0 + 4];
            float sm[8] = {sm0.x, sm0.y, sm0.z, sm0.w, sm1.x, sm1.y, sm1.z, sm1.w};
            float sq[8] = {sq0.x, sq0.y, sq0.z, sq0.w, sq1.x, sq1.y, sq1.z, sq1.w};
            float gm[8] = {gm0.x, gm0.y, gm0.z, gm0.w, gm1.x, gm1.y, gm1.z, gm1.w};
            float bt[8] = {bt0.x, bt0.y, bt0.z, bt0.w, bt1.x, bt1.y, bt1.z, bt1.w};
#pragma unroll
            for (int u = 0; u < 8; ++u) {
                float mu = sm[u] * invN;
                float s  = gm[u] * rsqrtf(sq[u] * invN - mu * mu + BN_EPS);
                sc[u] = s;
                sh[u] = bt[u] - mu * s;
            }
        }
#pragma unroll
        for (int i = 0; i < 2; ++i) {
            int row = row0 + i * 16 + r;
            int rrc = (row < N_NODES) ? row : (N_NODES - 1);
            uint4 av = *(const uint4*)(Ain + (size_t)rrc * 128 + k0);
            float y[8];
            y[0] = bf2f_lo(av.x); y[1] = bf2f_hi(av.x);
            y[2] = bf2f_lo(av.y); y[3] = bf2f_hi(av.y);
            y[4] = bf2f_lo(av.z); y[5] = bf2f_hi(av.z);
            y[6] = bf2f_lo(av.w); y[7] = bf2f_hi(av.w);
#pragma unroll
            for (int u = 0; u < 8; ++u) y[u] = y[u] * sc[u] + sh[u];
            if constexpr (MODE == 3) {
                uint4 rv = *(const uint4*)(RES + (size_t)rrc * 128 + k0);
                y[0] += bf2f_lo(rv.x); y[1] += bf2f_hi(rv.x);
                y[2] += bf2f_lo(rv.y); y[3] += bf2f_hi(rv.y);
                y[4] += bf2f_lo(rv.z); y[5] += bf2f_hi(rv.z);
                y[6] += bf2f_lo(rv.w); y[7] += bf2f_hi(rv.w);
            }
            uint4 o;
            o.x = (uint)f2bf(fmaxf(y[0], 0.f)) | ((uint)f2bf(fmaxf(y[1], 0.f)) << 16);
            o.y = (uint)f2bf(fmaxf(y[2], 0.f)) | ((uint)f2bf(fmaxf(y[3], 0.f)) << 16);
            o.z = (uint)f2bf(fmaxf(y[4], 0.f)) | ((uint)f2bf(fmaxf(y[5], 0.f)) << 16);
            o.w = (uint)f2bf(fmaxf(y[6], 0.f)) | ((uint)f2bf(fmaxf(y[7], 0.f)) << 16);
            afrag[ks][i] = __builtin_bit_cast(bf16x8, o);
            if (row < N_NODES)
                *(uint4*)(XOUT + (size_t)row * 128 + k0) = o;
        }
    }

    f32x4 acc[2][8];
#pragma unroll
    for (int i = 0; i < 2; ++i)
#pragma unroll
        for (int j = 0; j < 8; ++j)
            acc[i][j] = (f32x4){0.f, 0.f, 0.f, 0.f};

#pragma unroll
    for (int ks = 0; ks < 4; ++ks) {
        const int k0 = ks * 32 + q * 8;
        bf16x8 b[8];
#pragma unroll
        for (int j = 0; j < 8; ++j)
            b[j] = *(const bf16x8*)(Wt + (size_t)(j * 16 + r) * 128 + k0);
#pragma unroll
        for (int i = 0; i < 2; ++i)
#pragma unroll
            for (int j = 0; j < 8; ++j)
                acc[i][j] = __builtin_amdgcn_mfma_f32_16x16x32_bf16(afrag[ks][i], b[j], acc[i][j], 0, 0, 0);
    }

#pragma unroll
    for (int i = 0; i < 2; ++i) {
#pragma unroll
        for (int rg = 0; rg < 4; ++rg) {
            int rr = row0 + i * 16 + q * 4 + rg;
            if (rr < N_NODES) {
                float dv = dinv[rr];
#pragma unroll
                for (int j = 0; j < 8; ++j)
                    H[(size_t)rr * 128 + j * 16 + r] = f2bf(acc[i][j][rg] * dv);
            }
        }
    }
}

// ---------------- gather-aggregate (round-10 form): one wave per dst node ----------------
// 16 lanes per edge, uint4 (16B) loads; 16-edge main loop; VGPR 24 / occ ~70%.
// PRESCALED (layers 2,3): H rows already carry dinv_src ->
//     AGG = dinv_i*(sum H[s] + H[i]) + b
// !PRESCALED (layer 1): H unscaled ->
//     AGG = dinv_i*(sum dinv_s*H[s] + dinv_i*H[i]) + b
template<bool PRESCALED>
__global__ __launch_bounds__(256) void k_gather(const int* __restrict__ csr_src,
                                                const int* __restrict__ offs,
                                                const float* __restrict__ dinv,
                                                const ushort_t* __restrict__ H,
                                                const float* __restrict__ b,
                                                ushort_t* __restrict__ AGG) {
    int node = blockIdx.x * 4 + (threadIdx.x >> 6);
    if (node >= N_NODES) return;
    int lane = threadIdx.x & 63;
    int g = lane >> 4;             // edge slot within the quad (0..3)
    int cl = lane & 15;
    int c = cl * 8;                // 8 channels per lane

    float a0 = 0.f, a1 = 0.f, a2 = 0.f, a3 = 0.f;
    float a4 = 0.f, a5 = 0.f, a6 = 0.f, a7 = 0.f;
    float dvn = dinv[node];

#define ACC8(hv)  do { \
        a0 += bf2f_lo((hv).x); a1 += bf2f_hi((hv).x); \
        a2 += bf2f_lo((hv).y); a3 += bf2f_hi((hv).y); \
        a4 += bf2f_lo((hv).z); a5 += bf2f_hi((hv).z); \
        a6 += bf2f_lo((hv).w); a7 += bf2f_hi((hv).w); } while (0)
#define ACC8F(hv, dv)  do { \
        a0 = fmaf((dv), bf2f_lo((hv).x), a0); a1 = fmaf((dv), bf2f_hi((hv).x), a1); \
        a2 = fmaf((dv), bf2f_lo((hv).y), a2); a3 = fmaf((dv), bf2f_hi((hv).y), a3); \
        a4 = fmaf((dv), bf2f_lo((hv).z), a4); a5 = fmaf((dv), bf2f_hi((hv).z), a5); \
        a6 = fmaf((dv), bf2f_lo((hv).w), a6); a7 = fmaf((dv), bf2f_hi((hv).w), a7); } while (0)

    if (g == 0) {                  // self term
        uint4 hv = *(const uint4*)(H + (size_t)node * 128 + c);
        if constexpr (PRESCALED) { ACC8(hv); } else { ACC8F(hv, dvn); }
    }

    int p = offs[node];
    int end = offs[node + 1];

    for (; p + 16 <= end; p += 16) {          // 16 edges: 4 quad-loads in flight
        int s0 = csr_src[p      + g], s1 = csr_src[p +  4 + g];
        int s2 = csr_src[p +  8 + g], s3 = csr_src[p + 12 + g];
        uint4 h0 = *(const uint4*)(H + (size_t)s0 * 128 + c);
        uint4 h1 = *(const uint4*)(H + (size_t)s1 * 128 + c);
        uint4 h2 = *(const uint4*)(H + (size_t)s2 * 128 + c);
        uint4 h3 = *(const uint4*)(H + (size_t)s3 * 128 + c);
        if constexpr (PRESCALED) {
            ACC8(h0); ACC8(h1); ACC8(h2); ACC8(h3);
        } else {
            float d0 = dinv[s0], d1 = dinv[s1], d2 = dinv[s2], d3 = dinv[s3];
            ACC8F(h0, d0); ACC8F(h1, d1); ACC8F(h2, d2); ACC8F(h3, d3);
        }
    }
    for (; p + 4 <= end; p += 4) {            // 4 edges: 1 quad-load
        int s0 = csr_src[p + g];
        uint4 h0 = *(const uint4*)(H + (size_t)s0 * 128 + c);
        if constexpr (PRESCALED) { ACC8(h0); }
        else { float d0 = dinv[s0]; ACC8F(h0, d0); }
    }
    if (p < end) {                            // tail: 1-3 edges, predicated
        int idx = p + g;
        bool ok = idx < end;
        int s0 = csr_src[ok ? idx : p];
        uint4 h0 = *(const uint4*)(H + (size_t)s0 * 128 + c);
        if (ok) {
            if constexpr (PRESCALED) { ACC8(h0); }
            else { float d0 = dinv[s0]; ACC8F(h0, d0); }
        }
    }
#undef ACC8
#undef ACC8F

    // combine the 4 edge groups: xor 16 then xor 32
    a0 += __shfl_xor(a0, 16); a1 += __shfl_xor(a1, 16);
    a2 += __shfl_xor(a2, 16); a3 += __shfl_xor(a3, 16);
    a4 += __shfl_xor(a4, 16); a5 += __shfl_xor(a5, 16);
    a6 += __shfl_xor(a6, 16); a7 += __shfl_xor(a7, 16);
    a0 += __shfl_xor(a0, 32); a1 += __shfl_xor(a1, 32);
    a2 += __shfl_xor(a2, 32); a3 += __shfl_xor(a3, 32);
    a4 += __shfl_xor(a4, 32); a5 += __shfl_xor(a5, 32);
    a6 += __shfl_xor(a6, 32); a7 += __shfl_xor(a7, 32);

    if (g == 0) {
        float4 bv0 = *(const float4*)&b[c];
        float4 bv1 = *(const float4*)&b[c + 4];
        a0 = a0 * dvn + bv0.x; a1 = a1 * dvn + bv0.y;
        a2 = a2 * dvn + bv0.z; a3 = a3 * dvn + bv0.w;
        a4 = a4 * dvn + bv1.x; a5 = a5 * dvn + bv1.y;
        a6 = a6 * dvn + bv1.z; a7 = a7 * dvn + bv1.w;
        uint4 o;
        o.x = (uint)f2bf(a0) | ((uint)f2bf(a1) << 16);
        o.y = (uint)f2bf(a2) | ((uint)f2bf(a3) << 16);
        o.z = (uint)f2bf(a4) | ((uint)f2bf(a5) << 16);
        o.w = (uint)f2bf(a6) | ((uint)f2bf(a7) << 16);
        *(uint4*)(AGG + (size_t)node * 128 + c) = o;
    }
}

// ---------------- BN stats v2: uint2 loads, 16-way LDS reduce, 1 atomic/ch/block ----------------
// grid 256: 65K device-scope atomics; 256 blocks x 8 waves still saturate the read.
__global__ __launch_bounds__(512) void k_bn_stats(const ushort_t* __restrict__ AGG,
                                                  float* __restrict__ stats) {
    __shared__ float red[2][16][128];
    int c4 = (threadIdx.x & 31) * 4;
    int rl = threadIdx.x >> 5;          // 0..15 row-lanes
    float s0 = 0.f, s1 = 0.f, s2 = 0.f, s3 = 0.f;
    float q0 = 0.f, q1 = 0.f, q2 = 0.f, q3 = 0.f;
    for (int i = blockIdx.x * 16 + rl; i < N_NODES; i += gridDim.x * 16) {
        uint2 av = *(const uint2*)&AGG[(size_t)i * 128 + c4];
        float v0 = bf2f_lo(av.x), v1 = bf2f_hi(av.x);
        float v2 = bf2f_lo(av.y), v3 = bf2f_hi(av.y);
        s0 += v0; q0 += v0 * v0;
        s1 += v1; q1 += v1 * v1;
        s2 += v2; q2 += v2 * v2;
        s3 += v3; q3 += v3 * v3;
    }
    red[0][rl][c4 + 0] = s0; red[0][rl][c4 + 1] = s1;
    red[0][rl][c4 + 2] = s2; red[0][rl][c4 + 3] = s3;
    red[1][rl][c4 + 0] = q0; red[1][rl][c4 + 1] = q1;
    red[1][rl][c4 + 2] = q2; red[1][rl][c4 + 3] = q3;
    __syncthreads();
    int t = threadIdx.x;
    if (t < 128) {
        float S = 0.f;
#pragma unroll
        for (int k = 0; k < 16; ++k) S += red[0][k][t];
        atomicAdd(&stats[t], S);
    } else if (t < 256) {
        int c = t - 128;
        float Q = 0.f;
#pragma unroll
        for (int k = 0; k < 16; ++k) Q += red[1][k][c];
        atomicAdd(&stats[128 + c], Q);
    }
}

// ---------------- pooling v3: one block per graph, no atomics, head FUSED ----------------
// fused layer-3 bn_apply + relu + residual; per-graph range via binary search;
// head GEMV computed from LDS (psum/pmax never hit global).
__global__ __launch_bounds__(512) void k_pool(const ushort_t* __restrict__ AGG,
                                              const ushort_t* __restrict__ RES,
                                              const float* __restrict__ stats,
                                              const float* __restrict__ gamma,
                                              const float* __restrict__ beta,
                                              const int* __restrict__ batch,
                                              const float* __restrict__ Wh,
                                              const float* __restrict__ bh,
                                              float* __restrict__ out) {
    __shared__ int se[2];
    __shared__ float rs[16][128];
    __shared__ float rm[16][128];
    __shared__ float hp[8][64];
    int g = blockIdx.x;
    if (threadIdx.x < 2) {
        int target = g + (int)threadIdx.x;      // lower_bound(batch, target)
        int lo = 0, hi = N_NODES;
        while (lo < hi) {
            int mid = (lo + hi) >> 1;
            if (batch[mid] < target) lo = mid + 1; else hi = mid;
        }
        se[threadIdx.x] = lo;
    }
    __syncthreads();
    int i0 = se[0], i1 = se[1];

    int c4 = (threadIdx.x & 31) * 4;
    int rl = threadIdx.x >> 5;                  // 0..15

    const float invN = 1.0f / (float)N_NODES;
    float sc[4], sh[4];
#pragma unroll
    for (int u = 0; u < 4; ++u) {
        float mu = stats[c4 + u] * invN;
        float s = gamma[c4 + u] * rsqrtf(stats[128 + c4 + u] * invN - mu * mu + BN_EPS);
        sc[u] = s;
        sh[u] = beta[c4 + u] - mu * s;
    }

    float s0 = 0.f, s1 = 0.f, s2 = 0.f, s3 = 0.f;
    float m0 = 0.f, m1 = 0.f, m2 = 0.f, m3 = 0.f;
    for (int i = i0 + rl; i < i1; i += 16) {
        uint2 av = *(const uint2*)&AGG[(size_t)i * 128 + c4];
        uint2 rv = *(const uint2*)&RES[(size_t)i * 128 + c4];
        float v0 = fmaxf(bf2f_lo(av.x) * sc[0] + sh[0] + bf2f_lo(rv.x), 0.f);
        float v1 = fmaxf(bf2f_hi(av.x) * sc[1] + sh[1] + bf2f_hi(rv.x), 0.f);
        float v2 = fmaxf(bf2f_lo(av.y) * sc[2] + sh[2] + bf2f_lo(rv.y), 0.f);
        float v3 = fmaxf(bf2f_hi(av.y) * sc[3] + sh[3] + bf2f_hi(rv.y), 0.f);
        s0 += v0; m0 = fmaxf(m0, v0);
        s1 += v1; m1 = fmaxf(m1, v1);
        s2 += v2; m2 = fmaxf(m2, v2);
        s3 += v3; m3 = fmaxf(m3, v3);
    }
    rs[rl][c4 + 0] = s0; rs[rl][c4 + 1] = s1; rs[rl][c4 + 2] = s2; rs[rl][c4 + 3] = s3;
    rm[rl][c4 + 0] = m0; rm[rl][c4 + 1] = m1; rm[rl][c4 + 2] = m2; rm[rl][c4 + 3] = m3;
    __syncthreads();
    int t = threadIdx.x;
    if (t < 128) {
        float S = 0.f, M = 0.f;
#pragma unroll
        for (int k = 0; k < 16; ++k) {
            S += rs[k][t];
            M = fmaxf(M, rm[k][t]);
        }
        rs[0][t] = S;        // final per-channel sum
        rm[0][t] = M;        // final per-channel max
    }
    __syncthreads();

    // ---- fused head: out[g][o] = bh[o] + sum_c mean*Wh[c][o] + S*Wh[128+c][o] + M*Wh[256+c][o]
    float inv = 1.0f / fmaxf((float)(i1 - i0), 1.0f);
    int o = t & 63;
    int kc = t >> 6;                            // 0..7, 16 channels each
    float acc = 0.f;
#pragma unroll
    for (int u = 0; u < 16; ++u) {
        int c = kc * 16 + u;
        float S = rs[0][c];
        float M = rm[0][c];
        acc += (S * inv) * Wh[c * 64 + o];
        acc += S * Wh[(128 + c) * 64 + o];
        acc += M * Wh[(256 + c) * 64 + o];
    }
    hp[kc][o] = acc;
    __syncthreads();
    if (t < 64) {
        float r = bh[t];
#pragma unroll
        for (int k = 0; k < 8; ++k) r += hp[k][t];
        out[g * 64 + t] = r;
    }
}

// ---------------- host orchestration ----------------
extern "C" void kernel_launch(void* const* d_in, const int* in_sizes, int n_in,
                              void* d_out, int out_size, void* d_ws, size_t ws_size,
                              hipStream_t stream) {
    const float* x     = (const float*)d_in[0];
    const int*   ei    = (const int*)d_in[1];
    const int*   batch = (const int*)d_in[2];
    const float* W1 = (const float*)d_in[3];
    const float* b1 = (const float*)d_in[4];
    const float* g1 = (const float*)d_in[5];
    const float* be1= (const float*)d_in[6];
    const float* W2 = (const float*)d_in[7];
    const float* b2 = (const float*)d_in[8];
    const float* g2 = (const float*)d_in[9];
    const float* be2= (const float*)d_in[10];
    const float* W3 = (const float*)d_in[11];
    const float* b3 = (const float*)d_in[12];
    const float* g3 = (const float*)d_in[13];
    const float* be3= (const float*)d_in[14];
    const float* Wh = (const float*)d_in[15];
    const float* bh = (const float*)d_in[16];

    const int* src = ei;
    const int* dst = ei + N_EDGES;

    char* ws = (char*)d_ws;
    size_t off = 0;

    // ---- zero-initialized contiguous region (single memset) ----
    char* zero_base = ws;
    int*   cnt     = (int*)(ws + off);      off += 400384;                       // N_NODES*4 padded
    float* stats   = (float*)(ws + off);    off += 3 * 512 * 4;                  // 3 layers x 512 floats
    size_t zero_bytes = off;

    // ---- uninitialized scratch ----
    float* dinv    = (float*)(ws + off);    off += 512 * 1024;
    ushort_t* XBA  = (ushort_t*)(ws + off); off += (size_t)N_PAD * CH * 2;
    ushort_t* XBB  = (ushort_t*)(ws + off); off += (size_t)N_PAD * CH * 2;
    ushort_t* H    = (ushort_t*)(ws + off); off += (size_t)N_PAD * CH * 2;
    ushort_t* AGG  = (ushort_t*)(ws + off); off += (size_t)N_NODES * CH * 2;
    ushort_t* Wt   = (ushort_t*)(ws + off); off += 2 * 16384 * 2;               // layers 2,3 only
    int*   lofs    = (int*)(ws + off);      off += 512 * 1024;
    int*   offs    = (int*)(ws + off);      off += 512 * 1024;      // N+1 ints
    int*   bsum    = (int*)(ws + off);      off += 4096;
    int*   rank    = (int*)(ws + off);      off += (size_t)N_EDGES * 4;
    int*   csr_src = (int*)(ws + off);      off += (size_t)N_EDGES * 4;

    const int SCAN_BLOCKS = (N_NODES + 511) / 512;   // 196

    hipMemsetAsync(zero_base, 0, zero_bytes, stream);

    // mega-fused: layer-1 GEMM (FIRST: longest blocks) + W2/W3 transpose + degree count
    k_prep<<<GEMM1_BLOCKS + PREP_W_BLOCKS + DEG_BLOCKS, 256, 0, stream>>>(
        dst, cnt, rank, W1, W2, W3, Wt, x, H);

    k_scan1<<<SCAN_BLOCKS, 512, 0, stream>>>(cnt, lofs, bsum);
    k_scan3<<<(N_NODES + 255) / 256, 256, 0, stream>>>(lofs, bsum, cnt, offs, dinv, SCAN_BLOCKS);
    k_fill<<<(N_EDGES + 255) / 256, 256, 0, stream>>>(src, dst, offs, rank, csr_src);

    const int gemm_grid   = (N_NODES + 127) / 128;   // 782
    const int gather_grid = (N_NODES + 3) / 4;

    float* st1 = stats;
    float* st2 = stats + 512;
    float* st3 = stats + 1024;

    // layer 1 aggregation (H unscaled -> per-edge dinv fma)
    k_gather<false><<<gather_grid, 256, 0, stream>>>(csr_src, offs, dinv, H, b1, AGG);
    k_bn_stats<<<256, 512, 0, stream>>>(AGG, st1);

    // layer 2: A = relu(bn1(AGG)) in-register; writes h1 -> XBB
    k_gemm<2><<<gemm_grid, 256, 0, stream>>>(AGG, Wt, dinv, H,
                                             st1, g1, be1, nullptr, XBB);
    k_gather<true><<<gather_grid, 256, 0, stream>>>(csr_src, offs, dinv, H, b2, AGG);
    k_bn_stats<<<256, 512, 0, stream>>>(AGG, st2);

    // layer 3: A = relu(bn2(AGG) + h1) in-register; writes h2 -> XBA
    k_gemm<3><<<gemm_grid, 256, 0, stream>>>(AGG, Wt + 16384, dinv, H,
                                             st2, g2, be2, XBB, XBA);
    k_gather<true><<<gather_grid, 256, 0, stream>>>(csr_src, offs, dinv, H, b3, AGG);
    k_bn_stats<<<256, 512, 0, stream>>>(AGG, st3);

    // pooling (fused layer-3 bn_apply + relu + residual(h2) + HEAD), no atomics
    k_pool<<<N_GRAPHS, 512, 0, stream>>>(AGG, XBA, st3, g3, be3, batch, Wh, bh, (float*)d_out);
}